// Round 1
// baseline (1293.631 us; speedup 1.0000x reference)
//
#include <hip/hip_runtime.h>

#define NN 100000
#define EE 1600000
#define DD 128
#define HH 128
#define LL 3
#define GG 512
#define LATENT 64
#define BN_EPS 1e-5f
#define SLOPE 0.2f
#define NB_SCAN 391  // ceil(NN/256)

__device__ __forceinline__ float leaky(float t) { return t > 0.f ? t : SLOPE * t; }

// ---------------- CSR build ----------------

__global__ void hist_kernel(const int* __restrict__ dst, int* __restrict__ deg) {
    int e = blockIdx.x * blockDim.x + threadIdx.x;
    if (e < EE) atomicAdd(&deg[dst[e]], 1);
}

// pass 1: per-block (256-wide) sums of deg
__global__ __launch_bounds__(256) void scan1(const int* __restrict__ deg, int* __restrict__ bsum) {
    __shared__ int lds[256];
    int n = blockIdx.x * 256 + threadIdx.x;
    lds[threadIdx.x] = (n < NN) ? deg[n] : 0;
    __syncthreads();
    for (int off = 128; off > 0; off >>= 1) {
        if (threadIdx.x < off) lds[threadIdx.x] += lds[threadIdx.x + off];
        __syncthreads();
    }
    if (threadIdx.x == 0) bsum[blockIdx.x] = lds[0];
}

// pass 2: single-block exclusive scan of block sums (NB_SCAN=391 <= 512)
__global__ __launch_bounds__(512) void scan2(int* bsum, int* row_ptr) {
    __shared__ int lds[512];
    int tid = threadIdx.x;
    int v = (tid < NB_SCAN) ? bsum[tid] : 0;
    lds[tid] = v;
    __syncthreads();
    for (int off = 1; off < 512; off <<= 1) {
        int t = (tid >= off) ? lds[tid - off] : 0;
        __syncthreads();
        lds[tid] += t;
        __syncthreads();
    }
    int inc = lds[tid];
    if (tid < NB_SCAN) bsum[tid] = inc - v;       // exclusive block offsets
    if (tid == NB_SCAN - 1) row_ptr[NN] = inc;    // total == EE
}

// pass 3: per-element exclusive scan + block offset -> row_ptr, cursor
__global__ __launch_bounds__(256) void scan3(const int* __restrict__ deg, const int* __restrict__ bsumEx,
                                             int* __restrict__ row_ptr, int* __restrict__ cursor) {
    __shared__ int lds[256];
    int tid = threadIdx.x;
    int n = blockIdx.x * 256 + tid;
    int v = (n < NN) ? deg[n] : 0;
    lds[tid] = v;
    __syncthreads();
    for (int off = 1; off < 256; off <<= 1) {
        int t = (tid >= off) ? lds[tid - off] : 0;
        __syncthreads();
        lds[tid] += t;
        __syncthreads();
    }
    int ex = lds[tid] - v;
    if (n < NN) {
        int val = bsumEx[blockIdx.x] + ex;
        row_ptr[n] = val;
        cursor[n] = val;
    }
}

__global__ void fill_kernel(const int* __restrict__ src, const int* __restrict__ dst,
                            int* cursor, int* __restrict__ col) {
    int e = blockIdx.x * blockDim.x + threadIdx.x;
    if (e < EE) {
        int d = dst[e];
        int p = atomicAdd(&cursor[d], 1);
        col[p] = src[e];
    }
}

// graph start offsets from sorted batch
__global__ void gstart_kernel(const int* __restrict__ batch, int* __restrict__ gstart) {
    int n = blockIdx.x * blockDim.x + threadIdx.x;
    if (n >= NN) return;
    int b = batch[n];
    int pb = (n == 0) ? -1 : batch[n - 1];
    for (int g = pb + 1; g <= b; ++g) gstart[g] = n;
    if (n == NN - 1) {
        for (int g = b + 1; g <= GG; ++g) gstart[g] = NN;
    }
}

// ---------------- aggregation: u[n] = h[n] + sum_{j in in(n)} h[col[j]] ----------------
// one wave per node, float2 per lane (64 lanes * 8B = 512B row)
__global__ __launch_bounds__(256) void agg_kernel(const float* __restrict__ h,
                                                  const int* __restrict__ row_ptr,
                                                  const int* __restrict__ col,
                                                  float* __restrict__ u) {
    int wave = blockIdx.x * 4 + (threadIdx.x >> 6);
    int lane = threadIdx.x & 63;
    if (wave >= NN) return;
    const float2* hr = (const float2*)(h + (size_t)wave * HH);
    float2 acc = hr[lane];
    int s = row_ptr[wave], e = row_ptr[wave + 1];
    for (int j = s; j < e; ++j) {
        int c = col[j];
        const float2* cr = (const float2*)(h + (size_t)c * HH);
        float2 v = cr[lane];
        acc.x += v.x;
        acc.y += v.y;
    }
    ((float2*)(u + (size_t)wave * HH))[lane] = acc;
}

// ---------------- fused GEMM: Out = epilogue(A @ W + bias) ----------------
// A: [NN,128], W: [128,128]. Tile: 64 rows x 64 cols (blockIdx.y = col half).
// LDS: A-tile 32KB + W-half 32KB = 64KB -> 2 blocks/CU.
__global__ __launch_bounds__(256) void gemm_fused(const float* __restrict__ A,
                                                  const float* __restrict__ W,
                                                  const float* __restrict__ bias,
                                                  const float* __restrict__ g,
                                                  const float* __restrict__ beta,
                                                  const float* __restrict__ rm,
                                                  const float* __restrict__ rv,
                                                  float* __restrict__ Out, int doBN) {
    __shared__ float4 a4[64 * 32];   // 64 rows x 128 cols
    __shared__ float4 w4[128 * 16];  // 128 k x 64 cols (this block's half)
    const int tid = threadIdx.x;
    const int row0 = blockIdx.x * 64;
    const int chalf = blockIdx.y;

    const float4* Ag = (const float4*)A;
    for (int idx = tid; idx < 64 * 32; idx += 256) {
        int r = row0 + (idx >> 5);
        a4[idx] = (r < NN) ? Ag[(size_t)r * 32 + (idx & 31)] : make_float4(0.f, 0.f, 0.f, 0.f);
    }
    const float4* Wg = (const float4*)W;
    for (int idx = tid; idx < 128 * 16; idx += 256) {
        int k = idx >> 4;
        w4[idx] = Wg[k * 32 + chalf * 16 + (idx & 15)];
    }
    __syncthreads();

    const int tx = tid & 15;  // 4 cols each
    const int ty = tid >> 4;  // 4 rows each
    const float* a_lds = (const float*)a4;
    float acc[4][4] = {};
#pragma unroll 4
    for (int k = 0; k < 128; ++k) {
        float4 wv = w4[k * 16 + tx];
        float av[4];
#pragma unroll
        for (int i = 0; i < 4; ++i) av[i] = a_lds[(ty * 4 + i) * 128 + k];
#pragma unroll
        for (int i = 0; i < 4; ++i) {
            acc[i][0] += av[i] * wv.x;
            acc[i][1] += av[i] * wv.y;
            acc[i][2] += av[i] * wv.z;
            acc[i][3] += av[i] * wv.w;
        }
    }

    const int cb = chalf * 16 + tx;  // float4 col index 0..31
    float4 bv = ((const float4*)bias)[cb];
    float4 sc = make_float4(1.f, 1.f, 1.f, 1.f), sh = make_float4(0.f, 0.f, 0.f, 0.f);
    if (doBN) {
        float4 gv = ((const float4*)g)[cb];
        float4 bev = ((const float4*)beta)[cb];
        float4 rmv = ((const float4*)rm)[cb];
        float4 rvv = ((const float4*)rv)[cb];
        sc.x = gv.x * rsqrtf(rvv.x + BN_EPS); sh.x = bev.x - sc.x * rmv.x;
        sc.y = gv.y * rsqrtf(rvv.y + BN_EPS); sh.y = bev.y - sc.y * rmv.y;
        sc.z = gv.z * rsqrtf(rvv.z + BN_EPS); sh.z = bev.z - sc.z * rmv.z;
        sc.w = gv.w * rsqrtf(rvv.w + BN_EPS); sh.w = bev.w - sc.w * rmv.w;
    }
#pragma unroll
    for (int i = 0; i < 4; ++i) {
        int r = row0 + ty * 4 + i;
        if (r < NN) {
            float4 o;
            o.x = leaky(acc[i][0] + bv.x);
            o.y = leaky(acc[i][1] + bv.y);
            o.z = leaky(acc[i][2] + bv.z);
            o.w = leaky(acc[i][3] + bv.w);
            if (doBN) {
                o.x = sc.x * o.x + sh.x;
                o.y = sc.y * o.y + sh.y;
                o.z = sc.z * o.z + sh.z;
                o.w = sc.w * o.w + sh.w;
            }
            ((float4*)(Out + (size_t)r * HH))[cb] = o;
        }
    }
}

// ---------------- pooling + BN ----------------
__global__ __launch_bounds__(128) void pool_kernel(const float* __restrict__ h,
                                                   const int* __restrict__ gstart,
                                                   const float* __restrict__ bng,
                                                   const float* __restrict__ bnb,
                                                   const float* __restrict__ bnrm,
                                                   const float* __restrict__ bnrv,
                                                   float* __restrict__ pooled) {
    int g = blockIdx.x;
    int c = threadIdx.x;
    int s = gstart[g], e = gstart[g + 1];
    float acc = 0.f;
    for (int n = s; n < e; ++n) acc += h[(size_t)n * HH + c];
    float p = bng[c] * (acc - bnrm[c]) * rsqrtf(bnrv[c] + BN_EPS) + bnb[c];
    pooled[g * HH + c] = p;
}

// ---------------- final FC: out = pooled @ fcW + fcb ----------------
__global__ __launch_bounds__(64) void final_kernel(const float* __restrict__ pooled,
                                                   const float* __restrict__ fcW,
                                                   const float* __restrict__ fcb,
                                                   float* __restrict__ out) {
    int g = blockIdx.x;
    int l = threadIdx.x;
    float acc = fcb[l];
#pragma unroll 8
    for (int c = 0; c < HH; ++c) acc += pooled[g * HH + c] * fcW[c * LATENT + l];
    out[g * LATENT + l] = acc;
}

extern "C" void kernel_launch(void* const* d_in, const int* in_sizes, int n_in,
                              void* d_out, int out_size, void* d_ws, size_t ws_size,
                              hipStream_t stream) {
    const float* x = (const float*)d_in[0];
    const int* ei = (const int*)d_in[1];
    const int* batch = (const int*)d_in[2];
    const float* W1 = (const float*)d_in[3];
    const float* b1 = (const float*)d_in[4];
    const float* g1 = (const float*)d_in[5];
    const float* beta1 = (const float*)d_in[6];
    const float* rm1 = (const float*)d_in[7];
    const float* rv1 = (const float*)d_in[8];
    const float* W2 = (const float*)d_in[9];
    const float* b2 = (const float*)d_in[10];
    const float* bn_g = (const float*)d_in[11];
    const float* bn_b = (const float*)d_in[12];
    const float* bn_rm = (const float*)d_in[13];
    const float* bn_rv = (const float*)d_in[14];
    const float* fcW = (const float*)d_in[15];
    const float* fcb = (const float*)d_in[16];
    float* out = (float*)d_out;

    const int* src = ei;
    const int* dst = ei + EE;

    // workspace layout (1KB aligned)
    char* w = (char*)d_ws;
    size_t off = 0;
    auto alloc = [&](size_t bytes) -> char* {
        char* p = w + off;
        off += (bytes + 1023) & ~(size_t)1023;
        return p;
    };
    float* bufA = (float*)alloc(sizeof(float) * (size_t)NN * HH);  // h after each layer
    float* bufB = (float*)alloc(sizeof(float) * (size_t)NN * HH);  // u = h + agg
    float* bufC = (float*)alloc(sizeof(float) * (size_t)NN * HH);  // mid (post GEMM1)
    int* deg = (int*)alloc(4 * (size_t)NN);
    int* row_ptr = (int*)alloc(4 * (size_t)(NN + 1));
    int* cursor = (int*)alloc(4 * (size_t)NN);
    int* col = (int*)alloc(4 * (size_t)EE);
    int* bsum = (int*)alloc(4 * 512);
    int* gstart = (int*)alloc(4 * (GG + 1));
    float* pooled = (float*)alloc(sizeof(float) * GG * HH);
    (void)ws_size; (void)in_sizes; (void)n_in; (void)out_size;

    // CSR build
    hipMemsetAsync(deg, 0, 4 * (size_t)NN, stream);
    hist_kernel<<<(EE + 255) / 256, 256, 0, stream>>>(dst, deg);
    scan1<<<NB_SCAN, 256, 0, stream>>>(deg, bsum);
    scan2<<<1, 512, 0, stream>>>(bsum, row_ptr);
    scan3<<<NB_SCAN, 256, 0, stream>>>(deg, bsum, row_ptr, cursor);
    fill_kernel<<<(EE + 255) / 256, 256, 0, stream>>>(src, dst, cursor, col);
    gstart_kernel<<<(NN + 255) / 256, 256, 0, stream>>>(batch, gstart);

    dim3 ggrid((NN + 63) / 64, 2);
    const float* hcur = x;
    for (int i = 0; i < LL; ++i) {
        agg_kernel<<<(NN + 3) / 4, 256, 0, stream>>>(hcur, row_ptr, col, bufB);
        gemm_fused<<<ggrid, 256, 0, stream>>>(bufB, W1 + (size_t)i * DD * HH, b1 + i * HH,
                                              g1 + i * HH, beta1 + i * HH, rm1 + i * HH, rv1 + i * HH,
                                              bufC, 1);
        gemm_fused<<<ggrid, 256, 0, stream>>>(bufC, W2 + (size_t)i * HH * HH, b2 + i * HH,
                                              nullptr, nullptr, nullptr, nullptr,
                                              bufA, 0);
        hcur = bufA;
    }
    pool_kernel<<<GG, 128, 0, stream>>>(bufA, gstart, bn_g, bn_b, bn_rm, bn_rv, pooled);
    final_kernel<<<GG, 64, 0, stream>>>(pooled, fcW, fcb, out);
}

// Round 2
// 959.644 us; speedup vs baseline: 1.3480x; 1.3480x over previous
//
#include <hip/hip_runtime.h>

#define NN 100000
#define EE 1600000
#define DD 128
#define HH 128
#define LL 3
#define GG 512
#define LATENT 64
#define BN_EPS 1e-5f
#define SLOPE 0.2f
#define NB_SCAN 391  // ceil(NN/256)
#define ASTR 136     // padded LDS row stride (ushorts) to break 256B-stride bank conflicts

typedef __attribute__((ext_vector_type(8))) short short8;
typedef __attribute__((ext_vector_type(4))) float floatx4;

__device__ __forceinline__ float leaky(float t) { return t > 0.f ? t : SLOPE * t; }

// bf16 helpers (RNE)
__device__ __forceinline__ unsigned short f2bf(float x) {
    union { float f; unsigned int u; } v; v.f = x;
    unsigned int r = v.u + 0x7fffu + ((v.u >> 16) & 1u);
    return (unsigned short)(r >> 16);
}
__device__ __forceinline__ float bf_lo(unsigned int p) {
    union { unsigned int u; float f; } v; v.u = p << 16; return v.f;
}
__device__ __forceinline__ float bf_hi(unsigned int p) {
    union { unsigned int u; float f; } v; v.u = p & 0xffff0000u; return v.f;
}

// ---------------- CSR build ----------------

__global__ void hist_kernel(const int* __restrict__ dst, int* __restrict__ deg) {
    int e = blockIdx.x * blockDim.x + threadIdx.x;
    if (e < EE) atomicAdd(&deg[dst[e]], 1);
}

__global__ __launch_bounds__(256) void scan1(const int* __restrict__ deg, int* __restrict__ bsum) {
    __shared__ int lds[256];
    int n = blockIdx.x * 256 + threadIdx.x;
    lds[threadIdx.x] = (n < NN) ? deg[n] : 0;
    __syncthreads();
    for (int off = 128; off > 0; off >>= 1) {
        if (threadIdx.x < off) lds[threadIdx.x] += lds[threadIdx.x + off];
        __syncthreads();
    }
    if (threadIdx.x == 0) bsum[blockIdx.x] = lds[0];
}

__global__ __launch_bounds__(512) void scan2(int* bsum, int* row_ptr) {
    __shared__ int lds[512];
    int tid = threadIdx.x;
    int v = (tid < NB_SCAN) ? bsum[tid] : 0;
    lds[tid] = v;
    __syncthreads();
    for (int off = 1; off < 512; off <<= 1) {
        int t = (tid >= off) ? lds[tid - off] : 0;
        __syncthreads();
        lds[tid] += t;
        __syncthreads();
    }
    int inc = lds[tid];
    if (tid < NB_SCAN) bsum[tid] = inc - v;
    if (tid == NB_SCAN - 1) row_ptr[NN] = inc;
}

__global__ __launch_bounds__(256) void scan3(const int* __restrict__ deg, const int* __restrict__ bsumEx,
                                             int* __restrict__ row_ptr, int* __restrict__ cursor) {
    __shared__ int lds[256];
    int tid = threadIdx.x;
    int n = blockIdx.x * 256 + tid;
    int v = (n < NN) ? deg[n] : 0;
    lds[tid] = v;
    __syncthreads();
    for (int off = 1; off < 256; off <<= 1) {
        int t = (tid >= off) ? lds[tid - off] : 0;
        __syncthreads();
        lds[tid] += t;
        __syncthreads();
    }
    int ex = lds[tid] - v;
    if (n < NN) {
        int val = bsumEx[blockIdx.x] + ex;
        row_ptr[n] = val;
        cursor[n] = val;
    }
}

__global__ void fill_kernel(const int* __restrict__ src, const int* __restrict__ dst,
                            int* cursor, int* __restrict__ col) {
    int e = blockIdx.x * blockDim.x + threadIdx.x;
    if (e < EE) {
        int d = dst[e];
        int p = atomicAdd(&cursor[d], 1);
        col[p] = src[e];
    }
}

__global__ void gstart_kernel(const int* __restrict__ batch, int* __restrict__ gstart) {
    int n = blockIdx.x * blockDim.x + threadIdx.x;
    if (n >= NN) return;
    int b = batch[n];
    int pb = (n == 0) ? -1 : batch[n - 1];
    for (int g = pb + 1; g <= b; ++g) gstart[g] = n;
    if (n == NN - 1) {
        for (int g = b + 1; g <= GG; ++g) gstart[g] = NN;
    }
}

// ---------------- conversions ----------------

// x fp32 [NN*128] -> packed bf16x2 [NN*64]
__global__ __launch_bounds__(256) void cvtX(const float2* __restrict__ x2, unsigned int* __restrict__ hx) {
    int i = blockIdx.x * 256 + threadIdx.x;
    if (i >= NN * 64) return;
    float2 v = x2[i];
    hx[i] = (unsigned int)f2bf(v.x) | ((unsigned int)f2bf(v.y) << 16);
}

// W [128][128] fp32 row-major -> Wt [n][k] bf16 (i.e. W^T)
__global__ __launch_bounds__(256) void cvtW(const float* __restrict__ W, unsigned short* __restrict__ Wt) {
    int i = blockIdx.x * 256 + threadIdx.x;  // 16384
    int k = i >> 7, n = i & 127;
    Wt[n * 128 + k] = f2bf(W[k * 128 + n]);
}

// ---------------- aggregation (bf16): u[n] = h[n] + sum_{j in in(n)} h[col[j]] ----------------
// one wave per node; row = 128 bf16 = 64 uints, one uint (bf16x2) per lane
__global__ __launch_bounds__(256) void agg_bf16(const unsigned int* __restrict__ h,
                                                const int* __restrict__ row_ptr,
                                                const int* __restrict__ col,
                                                unsigned int* __restrict__ u) {
    int node = blockIdx.x * 4 + (threadIdx.x >> 6);
    int lane = threadIdx.x & 63;
    if (node >= NN) return;
    unsigned int p = h[(size_t)node * 64 + lane];
    float ax = bf_lo(p), ay = bf_hi(p);
    int s = row_ptr[node], e = row_ptr[node + 1];
    for (int j = s; j < e; ++j) {
        int c = col[j];
        unsigned int v = h[(size_t)c * 64 + lane];
        ax += bf_lo(v);
        ay += bf_hi(v);
    }
    u[(size_t)node * 64 + lane] = (unsigned int)f2bf(ax) | ((unsigned int)f2bf(ay) << 16);
}

// ---------------- MFMA GEMM: Out = epilogue(A @ W + bias), bf16 in/out, fp32 acc ----------------
// A [NN][128] bf16 row-major, Wt [128][128] bf16 = W^T. Block: 128 rows x 128 cols, 4 waves.
__global__ __launch_bounds__(256) void gemm_mfma(const unsigned short* __restrict__ A,
                                                 const unsigned short* __restrict__ Wt,
                                                 const float* __restrict__ bias,
                                                 const float* __restrict__ g,
                                                 const float* __restrict__ beta,
                                                 const float* __restrict__ rm,
                                                 const float* __restrict__ rv,
                                                 unsigned short* __restrict__ Out, int doBN) {
    __shared__ unsigned short aL[128 * ASTR];  // 34816 B
    __shared__ unsigned short bL[128 * ASTR];  // 34816 B
    const int tid = threadIdx.x;
    const int rb = blockIdx.x * 128;

    // stage A tile (rows rb..rb+127): 128 rows x 256 B = 2048 uint4
    const uint4* Ag = (const uint4*)(A + (size_t)rb * 128);
#pragma unroll
    for (int it = 0; it < 8; ++it) {
        int idx = it * 256 + tid;
        int r = idx >> 4, c = idx & 15;
        uint4 v = make_uint4(0u, 0u, 0u, 0u);
        if (rb + r < NN) v = Ag[idx];
        *(uint4*)&aL[r * ASTR + c * 8] = v;
    }
    // stage Wt (whole 128x128)
    const uint4* Wg = (const uint4*)Wt;
#pragma unroll
    for (int it = 0; it < 8; ++it) {
        int idx = it * 256 + tid;
        int r = idx >> 4, c = idx & 15;
        *(uint4*)&bL[r * ASTR + c * 8] = Wg[idx];
    }
    __syncthreads();

    const int wid = tid >> 6, lane = tid & 63;
    const int m0 = (wid >> 1) * 64, n0 = (wid & 1) * 64;
    const int ml = lane & 15, q = lane >> 4;

    floatx4 acc[4][4] = {};
#pragma unroll
    for (int kk = 0; kk < 4; ++kk) {
        const int k0 = kk * 32 + q * 8;
        short8 af[4], bf[4];
#pragma unroll
        for (int t = 0; t < 4; ++t)
            af[t] = *(const short8*)&aL[(m0 + t * 16 + ml) * ASTR + k0];
#pragma unroll
        for (int t = 0; t < 4; ++t)
            bf[t] = *(const short8*)&bL[(n0 + t * 16 + ml) * ASTR + k0];
#pragma unroll
        for (int tm = 0; tm < 4; ++tm)
#pragma unroll
            for (int tn = 0; tn < 4; ++tn)
                acc[tm][tn] = __builtin_amdgcn_mfma_f32_16x16x32_bf16(af[tm], bf[tn], acc[tm][tn], 0, 0, 0);
    }

    // epilogue params per tn (col = n0 + tn*16 + ml)
    float bv[4], sc[4], sh[4];
#pragma unroll
    for (int tn = 0; tn < 4; ++tn) {
        int c = n0 + tn * 16 + ml;
        bv[tn] = bias[c];
        if (doBN) {
            float s = g[c] * rsqrtf(rv[c] + BN_EPS);
            sc[tn] = s;
            sh[tn] = beta[c] - s * rm[c];
        } else {
            sc[tn] = 1.f;
            sh[tn] = 0.f;
        }
    }

#pragma unroll
    for (int tm = 0; tm < 4; ++tm) {
#pragma unroll
        for (int r = 0; r < 4; ++r) {
            int row = rb + m0 + tm * 16 + q * 4 + r;
            if (row < NN) {
#pragma unroll
                for (int tn = 0; tn < 4; ++tn) {
                    int c = n0 + tn * 16 + ml;
                    float val = leaky(acc[tm][tn][r] + bv[tn]);
                    val = sc[tn] * val + sh[tn];
                    Out[(size_t)row * 128 + c] = f2bf(val);
                }
            }
        }
    }
}

// ---------------- pooling + BN (bf16 input) ----------------
__global__ __launch_bounds__(128) void pool_bf16(const unsigned short* __restrict__ h,
                                                 const int* __restrict__ gstart,
                                                 const float* __restrict__ bng,
                                                 const float* __restrict__ bnb,
                                                 const float* __restrict__ bnrm,
                                                 const float* __restrict__ bnrv,
                                                 float* __restrict__ pooled) {
    int g = blockIdx.x;
    int c = threadIdx.x;
    int s = gstart[g], e = gstart[g + 1];
    float acc = 0.f;
    for (int n = s; n < e; ++n) {
        union { unsigned int u; float f; } v;
        v.u = ((unsigned int)h[(size_t)n * 128 + c]) << 16;
        acc += v.f;
    }
    float p = bng[c] * (acc - bnrm[c]) * rsqrtf(bnrv[c] + BN_EPS) + bnb[c];
    pooled[g * 128 + c] = p;
}

// ---------------- final FC ----------------
__global__ __launch_bounds__(64) void final_kernel(const float* __restrict__ pooled,
                                                   const float* __restrict__ fcW,
                                                   const float* __restrict__ fcb,
                                                   float* __restrict__ out) {
    int g = blockIdx.x;
    int l = threadIdx.x;
    float acc = fcb[l];
#pragma unroll 8
    for (int c = 0; c < HH; ++c) acc += pooled[g * 128 + c] * fcW[c * LATENT + l];
    out[g * LATENT + l] = acc;
}

extern "C" void kernel_launch(void* const* d_in, const int* in_sizes, int n_in,
                              void* d_out, int out_size, void* d_ws, size_t ws_size,
                              hipStream_t stream) {
    const float* x = (const float*)d_in[0];
    const int* ei = (const int*)d_in[1];
    const int* batch = (const int*)d_in[2];
    const float* W1 = (const float*)d_in[3];
    const float* b1 = (const float*)d_in[4];
    const float* g1 = (const float*)d_in[5];
    const float* beta1 = (const float*)d_in[6];
    const float* rm1 = (const float*)d_in[7];
    const float* rv1 = (const float*)d_in[8];
    const float* W2 = (const float*)d_in[9];
    const float* b2 = (const float*)d_in[10];
    const float* bn_g = (const float*)d_in[11];
    const float* bn_b = (const float*)d_in[12];
    const float* bn_rm = (const float*)d_in[13];
    const float* bn_rv = (const float*)d_in[14];
    const float* fcW = (const float*)d_in[15];
    const float* fcb = (const float*)d_in[16];
    float* out = (float*)d_out;

    const int* src = ei;
    const int* dst = ei + EE;

    char* w = (char*)d_ws;
    size_t off = 0;
    auto alloc = [&](size_t bytes) -> char* {
        char* p = w + off;
        off += (bytes + 1023) & ~(size_t)1023;
        return p;
    };
    unsigned int* hx = (unsigned int*)alloc(4 * (size_t)NN * 64);    // bf16 x
    unsigned int* ubuf = (unsigned int*)alloc(4 * (size_t)NN * 64);  // agg out
    unsigned int* mbuf = (unsigned int*)alloc(4 * (size_t)NN * 64);  // mid
    unsigned int* hbuf = (unsigned int*)alloc(4 * (size_t)NN * 64);  // layer out
    unsigned short* Wt = (unsigned short*)alloc(2 * (size_t)6 * 128 * 128);
    int* deg = (int*)alloc(4 * (size_t)NN);
    int* row_ptr = (int*)alloc(4 * (size_t)(NN + 1));
    int* cursor = (int*)alloc(4 * (size_t)NN);
    int* col = (int*)alloc(4 * (size_t)EE);
    int* bsum = (int*)alloc(4 * 512);
    int* gstart = (int*)alloc(4 * (GG + 1));
    float* pooled = (float*)alloc(sizeof(float) * GG * 128);
    (void)ws_size; (void)in_sizes; (void)n_in; (void)out_size;

    // CSR build
    hipMemsetAsync(deg, 0, 4 * (size_t)NN, stream);
    hist_kernel<<<(EE + 255) / 256, 256, 0, stream>>>(dst, deg);
    scan1<<<NB_SCAN, 256, 0, stream>>>(deg, bsum);
    scan2<<<1, 512, 0, stream>>>(bsum, row_ptr);
    scan3<<<NB_SCAN, 256, 0, stream>>>(deg, bsum, row_ptr, cursor);
    fill_kernel<<<(EE + 255) / 256, 256, 0, stream>>>(src, dst, cursor, col);
    gstart_kernel<<<(NN + 255) / 256, 256, 0, stream>>>(batch, gstart);

    // conversions
    cvtX<<<(NN * 64 + 255) / 256, 256, 0, stream>>>((const float2*)x, hx);
    for (int i = 0; i < LL; ++i) {
        cvtW<<<64, 256, 0, stream>>>(W1 + (size_t)i * DD * HH, Wt + (size_t)(2 * i) * 128 * 128);
        cvtW<<<64, 256, 0, stream>>>(W2 + (size_t)i * HH * HH, Wt + (size_t)(2 * i + 1) * 128 * 128);
    }

    const int gblocks = (NN + 127) / 128;
    const unsigned int* hcur = hx;
    for (int i = 0; i < LL; ++i) {
        agg_bf16<<<(NN + 3) / 4, 256, 0, stream>>>(hcur, row_ptr, col, ubuf);
        gemm_mfma<<<gblocks, 256, 0, stream>>>((const unsigned short*)ubuf,
                                               Wt + (size_t)(2 * i) * 128 * 128,
                                               b1 + i * HH, g1 + i * HH, beta1 + i * HH,
                                               rm1 + i * HH, rv1 + i * HH,
                                               (unsigned short*)mbuf, 1);
        gemm_mfma<<<gblocks, 256, 0, stream>>>((const unsigned short*)mbuf,
                                               Wt + (size_t)(2 * i + 1) * 128 * 128,
                                               b2 + i * HH, nullptr, nullptr, nullptr, nullptr,
                                               (unsigned short*)hbuf, 0);
        hcur = hbuf;
    }
    pool_bf16<<<GG, 128, 0, stream>>>((const unsigned short*)hbuf, gstart, bn_g, bn_b, bn_rm, bn_rv, pooled);
    final_kernel<<<GG, 64, 0, stream>>>(pooled, fcW, fcb, out);
}

// Round 3
// 671.521 us; speedup vs baseline: 1.9264x; 1.4291x over previous
//
#include <hip/hip_runtime.h>

#define NN 100000
#define EE 1600000
#define DD 128
#define HH 128
#define LL 3
#define GG 512
#define LATENT 64
#define BN_EPS 1e-5f
#define SLOPE 0.2f
#define NB_SCAN 391  // ceil(NN/256)
#define ASTR 136     // padded LDS row stride (ushorts) to break 256B-stride bank conflicts

typedef __attribute__((ext_vector_type(8))) short short8;
typedef __attribute__((ext_vector_type(4))) float floatx4;

__device__ __forceinline__ float leaky(float t) { return t > 0.f ? t : SLOPE * t; }

// bf16 helpers (RNE)
__device__ __forceinline__ unsigned short f2bf(float x) {
    union { float f; unsigned int u; } v; v.f = x;
    unsigned int r = v.u + 0x7fffu + ((v.u >> 16) & 1u);
    return (unsigned short)(r >> 16);
}
__device__ __forceinline__ float bf_lo(unsigned int p) {
    union { unsigned int u; float f; } v; v.u = p << 16; return v.f;
}
__device__ __forceinline__ float bf_hi(unsigned int p) {
    union { unsigned int u; float f; } v; v.u = p & 0xffff0000u; return v.f;
}

// ---------------- CSR build ----------------

__global__ void hist_kernel(const int* __restrict__ dst, int* __restrict__ deg) {
    int e = blockIdx.x * blockDim.x + threadIdx.x;
    if (e < EE) atomicAdd(&deg[dst[e]], 1);
}

__global__ __launch_bounds__(256) void scan1(const int* __restrict__ deg, int* __restrict__ bsum) {
    __shared__ int lds[256];
    int n = blockIdx.x * 256 + threadIdx.x;
    lds[threadIdx.x] = (n < NN) ? deg[n] : 0;
    __syncthreads();
    for (int off = 128; off > 0; off >>= 1) {
        if (threadIdx.x < off) lds[threadIdx.x] += lds[threadIdx.x + off];
        __syncthreads();
    }
    if (threadIdx.x == 0) bsum[blockIdx.x] = lds[0];
}

__global__ __launch_bounds__(512) void scan2(int* bsum, int* row_ptr) {
    __shared__ int lds[512];
    int tid = threadIdx.x;
    int v = (tid < NB_SCAN) ? bsum[tid] : 0;
    lds[tid] = v;
    __syncthreads();
    for (int off = 1; off < 512; off <<= 1) {
        int t = (tid >= off) ? lds[tid - off] : 0;
        __syncthreads();
        lds[tid] += t;
        __syncthreads();
    }
    int inc = lds[tid];
    if (tid < NB_SCAN) bsum[tid] = inc - v;
    if (tid == NB_SCAN - 1) row_ptr[NN] = inc;
}

__global__ __launch_bounds__(256) void scan3(const int* __restrict__ deg, const int* __restrict__ bsumEx,
                                             int* __restrict__ row_ptr, int* __restrict__ cursor) {
    __shared__ int lds[256];
    int tid = threadIdx.x;
    int n = blockIdx.x * 256 + tid;
    int v = (n < NN) ? deg[n] : 0;
    lds[tid] = v;
    __syncthreads();
    for (int off = 1; off < 256; off <<= 1) {
        int t = (tid >= off) ? lds[tid - off] : 0;
        __syncthreads();
        lds[tid] += t;
        __syncthreads();
    }
    int ex = lds[tid] - v;
    if (n < NN) {
        int val = bsumEx[blockIdx.x] + ex;
        row_ptr[n] = val;
        cursor[n] = val;
    }
}

__global__ void fill_kernel(const int* __restrict__ src, const int* __restrict__ dst,
                            int* cursor, int* __restrict__ col) {
    int e = blockIdx.x * blockDim.x + threadIdx.x;
    if (e < EE) {
        int d = dst[e];
        int p = atomicAdd(&cursor[d], 1);
        col[p] = src[e];
    }
}

__global__ void gstart_kernel(const int* __restrict__ batch, int* __restrict__ gstart) {
    int n = blockIdx.x * blockDim.x + threadIdx.x;
    if (n >= NN) return;
    int b = batch[n];
    int pb = (n == 0) ? -1 : batch[n - 1];
    for (int g = pb + 1; g <= b; ++g) gstart[g] = n;
    if (n == NN - 1) {
        for (int g = b + 1; g <= GG; ++g) gstart[g] = NN;
    }
}

// ---------------- conversions ----------------

__global__ __launch_bounds__(256) void cvtX(const float2* __restrict__ x2, unsigned int* __restrict__ hx) {
    int i = blockIdx.x * 256 + threadIdx.x;
    if (i >= NN * 64) return;
    float2 v = x2[i];
    hx[i] = (unsigned int)f2bf(v.x) | ((unsigned int)f2bf(v.y) << 16);
}

__global__ __launch_bounds__(256) void cvtW(const float* __restrict__ W, unsigned short* __restrict__ Wt) {
    int i = blockIdx.x * 256 + threadIdx.x;  // 16384
    int k = i >> 7, n = i & 127;
    Wt[n * 128 + k] = f2bf(W[k * 128 + n]);
}

// ---------------- aggregation (bf16, wide): u[n] = h[n] + sum_{j in in(n)} h[col[j]] ----------------
// One wave per node. Each lane loads uint4 (16B): lanes grp=lane>>4 process edge slot grp,
// sub=lane&15 indexes the row's 16 uint4 chunks. 4 edges in flight per iteration.
__global__ __launch_bounds__(256) void agg_bf16w(const unsigned int* __restrict__ h,
                                                 const int* __restrict__ row_ptr,
                                                 const int* __restrict__ col,
                                                 unsigned int* __restrict__ u) {
    int node = blockIdx.x * 4 + (threadIdx.x >> 6);
    int lane = threadIdx.x & 63;
    if (node >= NN) return;
    const int grp = lane >> 4;   // edge slot 0..3
    const int sub = lane & 15;   // uint4 chunk within row
    const uint4* hv = (const uint4*)h;  // 16 uint4 per row

    float a0 = 0.f, a1 = 0.f, a2 = 0.f, a3 = 0.f, a4 = 0.f, a5 = 0.f, a6 = 0.f, a7 = 0.f;
    // self contribution in group 0
    if (grp == 0) {
        uint4 v = hv[(size_t)node * 16 + sub];
        a0 += bf_lo(v.x); a1 += bf_hi(v.x);
        a2 += bf_lo(v.y); a3 += bf_hi(v.y);
        a4 += bf_lo(v.z); a5 += bf_hi(v.z);
        a6 += bf_lo(v.w); a7 += bf_hi(v.w);
    }
    int s = row_ptr[node], e = row_ptr[node + 1];
    for (int j = s + grp; j < e; j += 4) {
        int c = col[j];
        uint4 v = hv[(size_t)c * 16 + sub];
        a0 += bf_lo(v.x); a1 += bf_hi(v.x);
        a2 += bf_lo(v.y); a3 += bf_hi(v.y);
        a4 += bf_lo(v.z); a5 += bf_hi(v.z);
        a6 += bf_lo(v.w); a7 += bf_hi(v.w);
    }
    // butterfly across the 4 edge-slot groups (xor 16, 32)
    a0 += __shfl_xor(a0, 16); a0 += __shfl_xor(a0, 32);
    a1 += __shfl_xor(a1, 16); a1 += __shfl_xor(a1, 32);
    a2 += __shfl_xor(a2, 16); a2 += __shfl_xor(a2, 32);
    a3 += __shfl_xor(a3, 16); a3 += __shfl_xor(a3, 32);
    a4 += __shfl_xor(a4, 16); a4 += __shfl_xor(a4, 32);
    a5 += __shfl_xor(a5, 16); a5 += __shfl_xor(a5, 32);
    a6 += __shfl_xor(a6, 16); a6 += __shfl_xor(a6, 32);
    a7 += __shfl_xor(a7, 16); a7 += __shfl_xor(a7, 32);

    if (lane < 16) {
        uint4 o;
        o.x = (unsigned int)f2bf(a0) | ((unsigned int)f2bf(a1) << 16);
        o.y = (unsigned int)f2bf(a2) | ((unsigned int)f2bf(a3) << 16);
        o.z = (unsigned int)f2bf(a4) | ((unsigned int)f2bf(a5) << 16);
        o.w = (unsigned int)f2bf(a6) | ((unsigned int)f2bf(a7) << 16);
        ((uint4*)u)[(size_t)node * 16 + sub] = o;
    }
}

// ---------------- MFMA GEMM: Out = epilogue(A @ W + bias), bf16 in/out, fp32 acc ----------------
__global__ __launch_bounds__(256) void gemm_mfma(const unsigned short* __restrict__ A,
                                                 const unsigned short* __restrict__ Wt,
                                                 const float* __restrict__ bias,
                                                 const float* __restrict__ g,
                                                 const float* __restrict__ beta,
                                                 const float* __restrict__ rm,
                                                 const float* __restrict__ rv,
                                                 unsigned short* __restrict__ Out, int doBN) {
    __shared__ unsigned short aL[128 * ASTR];
    __shared__ unsigned short bL[128 * ASTR];
    const int tid = threadIdx.x;
    const int rb = blockIdx.x * 128;

    const uint4* Ag = (const uint4*)(A + (size_t)rb * 128);
#pragma unroll
    for (int it = 0; it < 8; ++it) {
        int idx = it * 256 + tid;
        int r = idx >> 4, c = idx & 15;
        uint4 v = make_uint4(0u, 0u, 0u, 0u);
        if (rb + r < NN) v = Ag[idx];
        *(uint4*)&aL[r * ASTR + c * 8] = v;
    }
    const uint4* Wg = (const uint4*)Wt;
#pragma unroll
    for (int it = 0; it < 8; ++it) {
        int idx = it * 256 + tid;
        int r = idx >> 4, c = idx & 15;
        *(uint4*)&bL[r * ASTR + c * 8] = Wg[idx];
    }
    __syncthreads();

    const int wid = tid >> 6, lane = tid & 63;
    const int m0 = (wid >> 1) * 64, n0 = (wid & 1) * 64;
    const int ml = lane & 15, q = lane >> 4;

    floatx4 acc[4][4] = {};
#pragma unroll
    for (int kk = 0; kk < 4; ++kk) {
        const int k0 = kk * 32 + q * 8;
        short8 af[4], bf[4];
#pragma unroll
        for (int t = 0; t < 4; ++t)
            af[t] = *(const short8*)&aL[(m0 + t * 16 + ml) * ASTR + k0];
#pragma unroll
        for (int t = 0; t < 4; ++t)
            bf[t] = *(const short8*)&bL[(n0 + t * 16 + ml) * ASTR + k0];
#pragma unroll
        for (int tm = 0; tm < 4; ++tm)
#pragma unroll
            for (int tn = 0; tn < 4; ++tn)
                acc[tm][tn] = __builtin_amdgcn_mfma_f32_16x16x32_bf16(af[tm], bf[tn], acc[tm][tn], 0, 0, 0);
    }

    float bv[4], sc[4], sh[4];
#pragma unroll
    for (int tn = 0; tn < 4; ++tn) {
        int c = n0 + tn * 16 + ml;
        bv[tn] = bias[c];
        if (doBN) {
            float s = g[c] * rsqrtf(rv[c] + BN_EPS);
            sc[tn] = s;
            sh[tn] = beta[c] - s * rm[c];
        } else {
            sc[tn] = 1.f;
            sh[tn] = 0.f;
        }
    }

#pragma unroll
    for (int tm = 0; tm < 4; ++tm) {
#pragma unroll
        for (int r = 0; r < 4; ++r) {
            int row = rb + m0 + tm * 16 + q * 4 + r;
            if (row < NN) {
#pragma unroll
                for (int tn = 0; tn < 4; ++tn) {
                    int c = n0 + tn * 16 + ml;
                    float val = leaky(acc[tm][tn][r] + bv[tn]);
                    val = sc[tn] * val + sh[tn];
                    Out[(size_t)row * 128 + c] = f2bf(val);
                }
            }
        }
    }
}

// ---------------- pooling + BN (bf16 input), 4 waves per graph ----------------
__global__ __launch_bounds__(256) void pool_bf16(const unsigned int* __restrict__ h,
                                                 const int* __restrict__ gstart,
                                                 const float* __restrict__ bng,
                                                 const float* __restrict__ bnb,
                                                 const float* __restrict__ bnrm,
                                                 const float* __restrict__ bnrv,
                                                 float* __restrict__ pooled) {
    __shared__ float lds[4][128];
    int g = blockIdx.x;
    int wid = threadIdx.x >> 6, lane = threadIdx.x & 63;
    int s = gstart[g], e = gstart[g + 1];
    float ax = 0.f, ay = 0.f;
    for (int n = s + wid; n < e; n += 4) {
        unsigned int v = h[(size_t)n * 64 + lane];
        ax += bf_lo(v);
        ay += bf_hi(v);
    }
    lds[wid][lane * 2] = ax;
    lds[wid][lane * 2 + 1] = ay;
    __syncthreads();
    if (wid == 0) {
        int c0 = lane * 2;
#pragma unroll
        for (int t = 0; t < 2; ++t) {
            int c = c0 + t;
            float acc = lds[0][c] + lds[1][c] + lds[2][c] + lds[3][c];
            float p = bng[c] * (acc - bnrm[c]) * rsqrtf(bnrv[c] + BN_EPS) + bnb[c];
            pooled[g * 128 + c] = p;
        }
    }
}

// ---------------- final FC ----------------
__global__ __launch_bounds__(64) void final_kernel(const float* __restrict__ pooled,
                                                   const float* __restrict__ fcW,
                                                   const float* __restrict__ fcb,
                                                   float* __restrict__ out) {
    int g = blockIdx.x;
    int l = threadIdx.x;
    float acc = fcb[l];
#pragma unroll 8
    for (int c = 0; c < HH; ++c) acc += pooled[g * 128 + c] * fcW[c * LATENT + l];
    out[g * LATENT + l] = acc;
}

extern "C" void kernel_launch(void* const* d_in, const int* in_sizes, int n_in,
                              void* d_out, int out_size, void* d_ws, size_t ws_size,
                              hipStream_t stream) {
    const float* x = (const float*)d_in[0];
    const int* ei = (const int*)d_in[1];
    const int* batch = (const int*)d_in[2];
    const float* W1 = (const float*)d_in[3];
    const float* b1 = (const float*)d_in[4];
    const float* g1 = (const float*)d_in[5];
    const float* beta1 = (const float*)d_in[6];
    const float* rm1 = (const float*)d_in[7];
    const float* rv1 = (const float*)d_in[8];
    const float* W2 = (const float*)d_in[9];
    const float* b2 = (const float*)d_in[10];
    const float* bn_g = (const float*)d_in[11];
    const float* bn_b = (const float*)d_in[12];
    const float* bn_rm = (const float*)d_in[13];
    const float* bn_rv = (const float*)d_in[14];
    const float* fcW = (const float*)d_in[15];
    const float* fcb = (const float*)d_in[16];
    float* out = (float*)d_out;

    const int* src = ei;
    const int* dst = ei + EE;

    char* w = (char*)d_ws;
    size_t off = 0;
    auto alloc = [&](size_t bytes) -> char* {
        char* p = w + off;
        off += (bytes + 1023) & ~(size_t)1023;
        return p;
    };
    unsigned int* hx = (unsigned int*)alloc(4 * (size_t)NN * 64);
    unsigned int* ubuf = (unsigned int*)alloc(4 * (size_t)NN * 64);
    unsigned int* mbuf = (unsigned int*)alloc(4 * (size_t)NN * 64);
    unsigned int* hbuf = (unsigned int*)alloc(4 * (size_t)NN * 64);
    unsigned short* Wt = (unsigned short*)alloc(2 * (size_t)6 * 128 * 128);
    int* deg = (int*)alloc(4 * (size_t)NN);
    int* row_ptr = (int*)alloc(4 * (size_t)(NN + 1));
    int* cursor = (int*)alloc(4 * (size_t)NN);
    int* col = (int*)alloc(4 * (size_t)EE);
    int* bsum = (int*)alloc(4 * 512);
    int* gstart = (int*)alloc(4 * (GG + 1));
    float* pooled = (float*)alloc(sizeof(float) * GG * 128);
    (void)ws_size; (void)in_sizes; (void)n_in; (void)out_size;

    hipMemsetAsync(deg, 0, 4 * (size_t)NN, stream);
    hist_kernel<<<(EE + 255) / 256, 256, 0, stream>>>(dst, deg);
    scan1<<<NB_SCAN, 256, 0, stream>>>(deg, bsum);
    scan2<<<1, 512, 0, stream>>>(bsum, row_ptr);
    scan3<<<NB_SCAN, 256, 0, stream>>>(deg, bsum, row_ptr, cursor);
    fill_kernel<<<(EE + 255) / 256, 256, 0, stream>>>(src, dst, cursor, col);
    gstart_kernel<<<(NN + 255) / 256, 256, 0, stream>>>(batch, gstart);

    cvtX<<<(NN * 64 + 255) / 256, 256, 0, stream>>>((const float2*)x, hx);
    for (int i = 0; i < LL; ++i) {
        cvtW<<<64, 256, 0, stream>>>(W1 + (size_t)i * DD * HH, Wt + (size_t)(2 * i) * 128 * 128);
        cvtW<<<64, 256, 0, stream>>>(W2 + (size_t)i * HH * HH, Wt + (size_t)(2 * i + 1) * 128 * 128);
    }

    const int gblocks = (NN + 127) / 128;
    const unsigned int* hcur = hx;
    for (int i = 0; i < LL; ++i) {
        agg_bf16w<<<(NN + 3) / 4, 256, 0, stream>>>(hcur, row_ptr, col, ubuf);
        gemm_mfma<<<gblocks, 256, 0, stream>>>((const unsigned short*)ubuf,
                                               Wt + (size_t)(2 * i) * 128 * 128,
                                               b1 + i * HH, g1 + i * HH, beta1 + i * HH,
                                               rm1 + i * HH, rv1 + i * HH,
                                               (unsigned short*)mbuf, 1);
        gemm_mfma<<<gblocks, 256, 0, stream>>>((const unsigned short*)mbuf,
                                               Wt + (size_t)(2 * i + 1) * 128 * 128,
                                               b2 + i * HH, nullptr, nullptr, nullptr, nullptr,
                                               (unsigned short*)hbuf, 0);
        hcur = hbuf;
    }
    pool_bf16<<<GG, 256, 0, stream>>>(hbuf, gstart, bn_g, bn_b, bn_rm, bn_rv, pooled);
    final_kernel<<<GG, 64, 0, stream>>>(pooled, fcW, fcb, out);
}

// Round 4
// 591.302 us; speedup vs baseline: 2.1878x; 1.1357x over previous
//
#include <hip/hip_runtime.h>

#define NN 100000
#define EE 1600000
#define DD 128
#define HH 128
#define LL 3
#define GG 512
#define LATENT 64
#define BN_EPS 1e-5f
#define SLOPE 0.2f
#define NB_SCAN 391  // ceil(NN/256)
#define ASTR 136     // padded LDS row stride (ushorts)

typedef __attribute__((ext_vector_type(8))) short short8;
typedef __attribute__((ext_vector_type(4))) float floatx4;

__device__ __forceinline__ float leaky(float t) { return t > 0.f ? t : SLOPE * t; }

__device__ __forceinline__ unsigned short f2bf(float x) {
    union { float f; unsigned int u; } v; v.f = x;
    unsigned int r = v.u + 0x7fffu + ((v.u >> 16) & 1u);
    return (unsigned short)(r >> 16);
}
__device__ __forceinline__ float bf_lo(unsigned int p) {
    union { unsigned int u; float f; } v; v.u = p << 16; return v.f;
}
__device__ __forceinline__ float bf_hi(unsigned int p) {
    union { unsigned int u; float f; } v; v.u = p & 0xffff0000u; return v.f;
}

// ---------------- CSR build ----------------

// hist + per-edge rank (the fetch-add we already pay yields the rank)
__global__ void hist_kernel(const int* __restrict__ dst, int* __restrict__ deg, int* __restrict__ rank) {
    int e = blockIdx.x * blockDim.x + threadIdx.x;
    if (e < EE) rank[e] = atomicAdd(&deg[dst[e]], 1);
}

__global__ __launch_bounds__(256) void scan1(const int* __restrict__ deg, int* __restrict__ bsum) {
    __shared__ int lds[256];
    int n = blockIdx.x * 256 + threadIdx.x;
    lds[threadIdx.x] = (n < NN) ? deg[n] : 0;
    __syncthreads();
    for (int off = 128; off > 0; off >>= 1) {
        if (threadIdx.x < off) lds[threadIdx.x] += lds[threadIdx.x + off];
        __syncthreads();
    }
    if (threadIdx.x == 0) bsum[blockIdx.x] = lds[0];
}

__global__ __launch_bounds__(512) void scan2(int* bsum, int* row_ptr) {
    __shared__ int lds[512];
    int tid = threadIdx.x;
    int v = (tid < NB_SCAN) ? bsum[tid] : 0;
    lds[tid] = v;
    __syncthreads();
    for (int off = 1; off < 512; off <<= 1) {
        int t = (tid >= off) ? lds[tid - off] : 0;
        __syncthreads();
        lds[tid] += t;
        __syncthreads();
    }
    int inc = lds[tid];
    if (tid < NB_SCAN) bsum[tid] = inc - v;
    if (tid == NB_SCAN - 1) row_ptr[NN] = inc;
}

__global__ __launch_bounds__(256) void scan3(const int* __restrict__ deg, const int* __restrict__ bsumEx,
                                             int* __restrict__ row_ptr) {
    __shared__ int lds[256];
    int tid = threadIdx.x;
    int n = blockIdx.x * 256 + tid;
    int v = (n < NN) ? deg[n] : 0;
    lds[tid] = v;
    __syncthreads();
    for (int off = 1; off < 256; off <<= 1) {
        int t = (tid >= off) ? lds[tid - off] : 0;
        __syncthreads();
        lds[tid] += t;
        __syncthreads();
    }
    int ex = lds[tid] - v;
    if (n < NN) row_ptr[n] = bsumEx[blockIdx.x] + ex;
}

// atomic-free scatter
__global__ void fill2(const int* __restrict__ src, const int* __restrict__ dst,
                      const int* __restrict__ rank, const int* __restrict__ row_ptr,
                      int* __restrict__ col) {
    int e = blockIdx.x * blockDim.x + threadIdx.x;
    if (e < EE) col[row_ptr[dst[e]] + rank[e]] = src[e];
}

__global__ void gstart_kernel(const int* __restrict__ batch, int* __restrict__ gstart) {
    int n = blockIdx.x * blockDim.x + threadIdx.x;
    if (n >= NN) return;
    int b = batch[n];
    int pb = (n == 0) ? -1 : batch[n - 1];
    for (int g = pb + 1; g <= b; ++g) gstart[g] = n;
    if (n == NN - 1) {
        for (int g = b + 1; g <= GG; ++g) gstart[g] = NN;
    }
}

// ---------------- conversions ----------------

__global__ __launch_bounds__(256) void cvtX(const float2* __restrict__ x2, unsigned int* __restrict__ hx) {
    int i = blockIdx.x * 256 + threadIdx.x;
    if (i >= NN * 64) return;
    float2 v = x2[i];
    hx[i] = (unsigned int)f2bf(v.x) | ((unsigned int)f2bf(v.y) << 16);
}

// W [k][n] fp32 -> fragment-linear bf16: Wf[((kk*8+tn)*64+lane)] = uint4 of
// W^T rows n=tn*16+(lane&15), k = kk*32+(lane>>4)*8 .. +7
__global__ __launch_bounds__(256) void cvtWfrag(const float* __restrict__ W, uint4* __restrict__ Wf) {
    int t = blockIdx.x * 256 + threadIdx.x;  // 2048 total
    if (t >= 2048) return;
    int lane = t & 63;
    int tn = (t >> 6) & 7;
    int kk = t >> 9;
    int n = tn * 16 + (lane & 15);
    int kb = kk * 32 + (lane >> 4) * 8;
    unsigned int p[4];
#pragma unroll
    for (int jj = 0; jj < 4; ++jj) {
        unsigned short lo = f2bf(W[(kb + 2 * jj) * 128 + n]);
        unsigned short hi = f2bf(W[(kb + 2 * jj + 1) * 128 + n]);
        p[jj] = (unsigned int)lo | ((unsigned int)hi << 16);
    }
    Wf[t] = make_uint4(p[0], p[1], p[2], p[3]);
}

// ---------------- aggregation (bf16, wide) ----------------
__global__ __launch_bounds__(256) void agg_bf16w(const unsigned int* __restrict__ h,
                                                 const int* __restrict__ row_ptr,
                                                 const int* __restrict__ col,
                                                 unsigned int* __restrict__ u) {
    int node = blockIdx.x * 4 + (threadIdx.x >> 6);
    int lane = threadIdx.x & 63;
    if (node >= NN) return;
    const int grp = lane >> 4;
    const int sub = lane & 15;
    const uint4* hv = (const uint4*)h;

    float a0 = 0.f, a1 = 0.f, a2 = 0.f, a3 = 0.f, a4 = 0.f, a5 = 0.f, a6 = 0.f, a7 = 0.f;
    if (grp == 0) {
        uint4 v = hv[(size_t)node * 16 + sub];
        a0 += bf_lo(v.x); a1 += bf_hi(v.x);
        a2 += bf_lo(v.y); a3 += bf_hi(v.y);
        a4 += bf_lo(v.z); a5 += bf_hi(v.z);
        a6 += bf_lo(v.w); a7 += bf_hi(v.w);
    }
    int s = row_ptr[node], e = row_ptr[node + 1];
    for (int j = s + grp; j < e; j += 4) {
        int c = col[j];
        uint4 v = hv[(size_t)c * 16 + sub];
        a0 += bf_lo(v.x); a1 += bf_hi(v.x);
        a2 += bf_lo(v.y); a3 += bf_hi(v.y);
        a4 += bf_lo(v.z); a5 += bf_hi(v.z);
        a6 += bf_lo(v.w); a7 += bf_hi(v.w);
    }
    a0 += __shfl_xor(a0, 16); a0 += __shfl_xor(a0, 32);
    a1 += __shfl_xor(a1, 16); a1 += __shfl_xor(a1, 32);
    a2 += __shfl_xor(a2, 16); a2 += __shfl_xor(a2, 32);
    a3 += __shfl_xor(a3, 16); a3 += __shfl_xor(a3, 32);
    a4 += __shfl_xor(a4, 16); a4 += __shfl_xor(a4, 32);
    a5 += __shfl_xor(a5, 16); a5 += __shfl_xor(a5, 32);
    a6 += __shfl_xor(a6, 16); a6 += __shfl_xor(a6, 32);
    a7 += __shfl_xor(a7, 16); a7 += __shfl_xor(a7, 32);

    if (lane < 16) {
        uint4 o;
        o.x = (unsigned int)f2bf(a0) | ((unsigned int)f2bf(a1) << 16);
        o.y = (unsigned int)f2bf(a2) | ((unsigned int)f2bf(a3) << 16);
        o.z = (unsigned int)f2bf(a4) | ((unsigned int)f2bf(a5) << 16);
        o.w = (unsigned int)f2bf(a6) | ((unsigned int)f2bf(a7) << 16);
        ((uint4*)u)[(size_t)node * 16 + sub] = o;
    }
}

// ---------------- fused MLP: Out = leaky(BN(leaky(A@W1+b1))@W2 + b2) ----------------
// Block = 256 thr / 4 waves, 128-row tile. Wave w owns rows m0=w*32, all 128 cols.
// W fragments read directly from global (L2-resident, fragment-linear layout).
__global__ __launch_bounds__(256) void mlp_fused(const unsigned short* __restrict__ A,
                                                 const uint4* __restrict__ W1f,
                                                 const uint4* __restrict__ W2f,
                                                 const float* __restrict__ b1,
                                                 const float* __restrict__ g,
                                                 const float* __restrict__ beta,
                                                 const float* __restrict__ rm,
                                                 const float* __restrict__ rv,
                                                 const float* __restrict__ b2,
                                                 unsigned short* __restrict__ Out) {
    __shared__ unsigned short aL[128 * ASTR];      // 34816 B
    __shared__ unsigned short mL[4][32 * ASTR];    // 34816 B (per-wave mid)
    const int tid = threadIdx.x;
    const int rb = blockIdx.x * 128;

    const uint4* Ag = (const uint4*)(A + (size_t)rb * 128);
#pragma unroll
    for (int it = 0; it < 8; ++it) {
        int idx = it * 256 + tid;
        int r = idx >> 4, c = idx & 15;
        uint4 v = make_uint4(0u, 0u, 0u, 0u);
        if (rb + r < NN) v = Ag[idx];
        *(uint4*)&aL[r * ASTR + c * 8] = v;
    }
    __syncthreads();

    const int wid = tid >> 6, lane = tid & 63;
    const int ml = lane & 15, q = lane >> 4;
    const int m0 = wid * 32;

    floatx4 acc[2][8] = {};
#pragma unroll
    for (int kk = 0; kk < 4; ++kk) {
        short8 af[2];
#pragma unroll
        for (int t = 0; t < 2; ++t)
            af[t] = *(const short8*)&aL[(m0 + t * 16 + ml) * ASTR + kk * 32 + q * 8];
#pragma unroll
        for (int tn = 0; tn < 8; ++tn) {
            uint4 bq = W1f[(kk * 8 + tn) * 64 + lane];
            short8 bf = *(short8*)&bq;
            acc[0][tn] = __builtin_amdgcn_mfma_f32_16x16x32_bf16(af[0], bf, acc[0][tn], 0, 0, 0);
            acc[1][tn] = __builtin_amdgcn_mfma_f32_16x16x32_bf16(af[1], bf, acc[1][tn], 0, 0, 0);
        }
    }

    // epilogue 1: bias + leaky + BN -> per-wave LDS mid (bf16)
#pragma unroll
    for (int tn = 0; tn < 8; ++tn) {
        int c = tn * 16 + ml;
        float s = g[c] * rsqrtf(rv[c] + BN_EPS);
        float sh = beta[c] - s * rm[c];
        float bv = b1[c];
#pragma unroll
        for (int t = 0; t < 2; ++t)
#pragma unroll
            for (int r = 0; r < 4; ++r) {
                float val = leaky(acc[t][tn][r] + bv);
                val = s * val + sh;
                mL[wid][(t * 16 + q * 4 + r) * ASTR + c] = f2bf(val);
            }
    }
    __syncthreads();

    floatx4 acc2[2][8] = {};
#pragma unroll
    for (int kk = 0; kk < 4; ++kk) {
        short8 af[2];
#pragma unroll
        for (int t = 0; t < 2; ++t)
            af[t] = *(const short8*)&mL[wid][(t * 16 + ml) * ASTR + kk * 32 + q * 8];
#pragma unroll
        for (int tn = 0; tn < 8; ++tn) {
            uint4 bq = W2f[(kk * 8 + tn) * 64 + lane];
            short8 bf = *(short8*)&bq;
            acc2[0][tn] = __builtin_amdgcn_mfma_f32_16x16x32_bf16(af[0], bf, acc2[0][tn], 0, 0, 0);
            acc2[1][tn] = __builtin_amdgcn_mfma_f32_16x16x32_bf16(af[1], bf, acc2[1][tn], 0, 0, 0);
        }
    }

#pragma unroll
    for (int tn = 0; tn < 8; ++tn) {
        int c = tn * 16 + ml;
        float bv = b2[c];
#pragma unroll
        for (int t = 0; t < 2; ++t)
#pragma unroll
            for (int r = 0; r < 4; ++r) {
                int row = rb + m0 + t * 16 + q * 4 + r;
                if (row < NN)
                    Out[(size_t)row * 128 + c] = f2bf(leaky(acc2[t][tn][r] + bv));
            }
    }
}

// ---------------- pooling + BN ----------------
__global__ __launch_bounds__(256) void pool_bf16(const unsigned int* __restrict__ h,
                                                 const int* __restrict__ gstart,
                                                 const float* __restrict__ bng,
                                                 const float* __restrict__ bnb,
                                                 const float* __restrict__ bnrm,
                                                 const float* __restrict__ bnrv,
                                                 float* __restrict__ pooled) {
    __shared__ float lds[4][128];
    int g = blockIdx.x;
    int wid = threadIdx.x >> 6, lane = threadIdx.x & 63;
    int s = gstart[g], e = gstart[g + 1];
    float ax = 0.f, ay = 0.f;
    for (int n = s + wid; n < e; n += 4) {
        unsigned int v = h[(size_t)n * 64 + lane];
        ax += bf_lo(v);
        ay += bf_hi(v);
    }
    lds[wid][lane * 2] = ax;
    lds[wid][lane * 2 + 1] = ay;
    __syncthreads();
    if (wid == 0) {
#pragma unroll
        for (int t = 0; t < 2; ++t) {
            int c = lane * 2 + t;
            float acc = lds[0][c] + lds[1][c] + lds[2][c] + lds[3][c];
            pooled[g * 128 + c] = bng[c] * (acc - bnrm[c]) * rsqrtf(bnrv[c] + BN_EPS) + bnb[c];
        }
    }
}

__global__ __launch_bounds__(64) void final_kernel(const float* __restrict__ pooled,
                                                   const float* __restrict__ fcW,
                                                   const float* __restrict__ fcb,
                                                   float* __restrict__ out) {
    int g = blockIdx.x;
    int l = threadIdx.x;
    float acc = fcb[l];
#pragma unroll 8
    for (int c = 0; c < HH; ++c) acc += pooled[g * 128 + c] * fcW[c * LATENT + l];
    out[g * LATENT + l] = acc;
}

extern "C" void kernel_launch(void* const* d_in, const int* in_sizes, int n_in,
                              void* d_out, int out_size, void* d_ws, size_t ws_size,
                              hipStream_t stream) {
    const float* x = (const float*)d_in[0];
    const int* ei = (const int*)d_in[1];
    const int* batch = (const int*)d_in[2];
    const float* W1 = (const float*)d_in[3];
    const float* b1 = (const float*)d_in[4];
    const float* g1 = (const float*)d_in[5];
    const float* beta1 = (const float*)d_in[6];
    const float* rm1 = (const float*)d_in[7];
    const float* rv1 = (const float*)d_in[8];
    const float* W2 = (const float*)d_in[9];
    const float* b2 = (const float*)d_in[10];
    const float* bn_g = (const float*)d_in[11];
    const float* bn_b = (const float*)d_in[12];
    const float* bn_rm = (const float*)d_in[13];
    const float* bn_rv = (const float*)d_in[14];
    const float* fcW = (const float*)d_in[15];
    const float* fcb = (const float*)d_in[16];
    float* out = (float*)d_out;

    const int* src = ei;
    const int* dst = ei + EE;

    char* w = (char*)d_ws;
    size_t off = 0;
    auto alloc = [&](size_t bytes) -> char* {
        char* p = w + off;
        off += (bytes + 1023) & ~(size_t)1023;
        return p;
    };
    unsigned int* hx = (unsigned int*)alloc(4 * (size_t)NN * 64);
    unsigned int* ubuf = (unsigned int*)alloc(4 * (size_t)NN * 64);
    unsigned int* hbuf = (unsigned int*)alloc(4 * (size_t)NN * 64);
    uint4* Wf = (uint4*)alloc(16 * (size_t)6 * 2048);  // 6 matrices x 2048 uint4
    int* deg = (int*)alloc(4 * (size_t)NN);
    int* row_ptr = (int*)alloc(4 * (size_t)(NN + 1));
    int* rank = (int*)alloc(4 * (size_t)EE);
    int* col = (int*)alloc(4 * (size_t)EE);
    int* bsum = (int*)alloc(4 * 512);
    int* gstart = (int*)alloc(4 * (GG + 1));
    float* pooled = (float*)alloc(sizeof(float) * GG * 128);
    (void)ws_size; (void)in_sizes; (void)n_in; (void)out_size;

    hipMemsetAsync(deg, 0, 4 * (size_t)NN, stream);
    hist_kernel<<<(EE + 255) / 256, 256, 0, stream>>>(dst, deg, rank);
    scan1<<<NB_SCAN, 256, 0, stream>>>(deg, bsum);
    scan2<<<1, 512, 0, stream>>>(bsum, row_ptr);
    scan3<<<NB_SCAN, 256, 0, stream>>>(deg, bsum, row_ptr);
    fill2<<<(EE + 255) / 256, 256, 0, stream>>>(src, dst, rank, row_ptr, col);
    gstart_kernel<<<(NN + 255) / 256, 256, 0, stream>>>(batch, gstart);

    cvtX<<<(NN * 64 + 255) / 256, 256, 0, stream>>>((const float2*)x, hx);
    for (int i = 0; i < LL; ++i) {
        cvtWfrag<<<8, 256, 0, stream>>>(W1 + (size_t)i * DD * HH, Wf + (size_t)(2 * i) * 2048);
        cvtWfrag<<<8, 256, 0, stream>>>(W2 + (size_t)i * HH * HH, Wf + (size_t)(2 * i + 1) * 2048);
    }

    const int gblocks = (NN + 127) / 128;
    const unsigned int* hcur = hx;
    for (int i = 0; i < LL; ++i) {
        agg_bf16w<<<(NN + 3) / 4, 256, 0, stream>>>(hcur, row_ptr, col, ubuf);
        mlp_fused<<<gblocks, 256, 0, stream>>>((const unsigned short*)ubuf,
                                               Wf + (size_t)(2 * i) * 2048,
                                               Wf + (size_t)(2 * i + 1) * 2048,
                                               b1 + i * HH, g1 + i * HH, beta1 + i * HH,
                                               rm1 + i * HH, rv1 + i * HH, b2 + i * HH,
                                               (unsigned short*)hbuf);
        hcur = hbuf;
    }
    pool_bf16<<<GG, 256, 0, stream>>>(hbuf, gstart, bn_g, bn_b, bn_rm, bn_rv, pooled);
    final_kernel<<<GG, 64, 0, stream>>>(pooled, fcW, fcb, out);
}

// Round 5
// 563.208 us; speedup vs baseline: 2.2969x; 1.0499x over previous
//
#include <hip/hip_runtime.h>

#define NN 100000
#define EE 1600000
#define DD 128
#define HH 128
#define LL 3
#define GG 512
#define LATENT 64
#define BN_EPS 1e-5f
#define SLOPE 0.2f
#define NB_SCAN 391  // ceil(NN/256)
#define ASTR 136     // padded LDS row stride (ushorts)

typedef __attribute__((ext_vector_type(8))) short short8;
typedef __attribute__((ext_vector_type(4))) float floatx4;

__device__ __forceinline__ float leaky(float t) { return t > 0.f ? t : SLOPE * t; }

__device__ __forceinline__ unsigned short f2bf(float x) {
    union { float f; unsigned int u; } v; v.f = x;
    unsigned int r = v.u + 0x7fffu + ((v.u >> 16) & 1u);
    return (unsigned short)(r >> 16);
}
__device__ __forceinline__ float bf_lo(unsigned int p) {
    union { unsigned int u; float f; } v; v.u = p << 16; return v.f;
}
__device__ __forceinline__ float bf_hi(unsigned int p) {
    union { unsigned int u; float f; } v; v.u = p & 0xffff0000u; return v.f;
}

// ---------------- CSR build ----------------

__global__ void hist_kernel(const int* __restrict__ dst, int* __restrict__ deg, int* __restrict__ rank) {
    int e = blockIdx.x * blockDim.x + threadIdx.x;
    if (e < EE) rank[e] = atomicAdd(&deg[dst[e]], 1);
}

__global__ __launch_bounds__(256) void scan1(const int* __restrict__ deg, int* __restrict__ bsum) {
    __shared__ int lds[256];
    int n = blockIdx.x * 256 + threadIdx.x;
    lds[threadIdx.x] = (n < NN) ? deg[n] : 0;
    __syncthreads();
    for (int off = 128; off > 0; off >>= 1) {
        if (threadIdx.x < off) lds[threadIdx.x] += lds[threadIdx.x + off];
        __syncthreads();
    }
    if (threadIdx.x == 0) bsum[blockIdx.x] = lds[0];
}

__global__ __launch_bounds__(512) void scan2(int* bsum, int* row_ptr) {
    __shared__ int lds[512];
    int tid = threadIdx.x;
    int v = (tid < NB_SCAN) ? bsum[tid] : 0;
    lds[tid] = v;
    __syncthreads();
    for (int off = 1; off < 512; off <<= 1) {
        int t = (tid >= off) ? lds[tid - off] : 0;
        __syncthreads();
        lds[tid] += t;
        __syncthreads();
    }
    int inc = lds[tid];
    if (tid < NB_SCAN) bsum[tid] = inc - v;
    if (tid == NB_SCAN - 1) row_ptr[NN] = inc;
}

__global__ __launch_bounds__(256) void scan3(const int* __restrict__ deg, const int* __restrict__ bsumEx,
                                             int* __restrict__ row_ptr) {
    __shared__ int lds[256];
    int tid = threadIdx.x;
    int n = blockIdx.x * 256 + tid;
    int v = (n < NN) ? deg[n] : 0;
    lds[tid] = v;
    __syncthreads();
    for (int off = 1; off < 256; off <<= 1) {
        int t = (tid >= off) ? lds[tid - off] : 0;
        __syncthreads();
        lds[tid] += t;
        __syncthreads();
    }
    int ex = lds[tid] - v;
    if (n < NN) row_ptr[n] = bsumEx[blockIdx.x] + ex;
}

__global__ void fill2(const int* __restrict__ src, const int* __restrict__ dst,
                      const int* __restrict__ rank, const int* __restrict__ row_ptr,
                      int* __restrict__ col) {
    int e = blockIdx.x * blockDim.x + threadIdx.x;
    if (e < EE) col[row_ptr[dst[e]] + rank[e]] = src[e];
}

__global__ void gstart_kernel(const int* __restrict__ batch, int* __restrict__ gstart) {
    int n = blockIdx.x * blockDim.x + threadIdx.x;
    if (n >= NN) return;
    int b = batch[n];
    int pb = (n == 0) ? -1 : batch[n - 1];
    for (int g = pb + 1; g <= b; ++g) gstart[g] = n;
    if (n == NN - 1) {
        for (int g = b + 1; g <= GG; ++g) gstart[g] = NN;
    }
}

// ---------------- conversions ----------------

__global__ __launch_bounds__(256) void cvtX(const float2* __restrict__ x2, unsigned int* __restrict__ hx) {
    int i = blockIdx.x * 256 + threadIdx.x;
    if (i >= NN * 64) return;
    float2 v = x2[i];
    hx[i] = (unsigned int)f2bf(v.x) | ((unsigned int)f2bf(v.y) << 16);
}

// all 6 weight matrices -> fragment-linear bf16 in one launch
// Wf[mat*2048 + (kk*8+tn)*64 + lane] = uint4 of W^T rows n=tn*16+(lane&15), k=kk*32+(lane>>4)*8..+7
__global__ __launch_bounds__(256) void cvtWall(const float* __restrict__ W1,
                                               const float* __restrict__ W2,
                                               uint4* __restrict__ Wf) {
    int t = blockIdx.x * 256 + threadIdx.x;  // 6*2048 total
    if (t >= 6 * 2048) return;
    int mat = t >> 11;
    int idx = t & 2047;
    const float* W = ((mat & 1) ? W2 : W1) + (size_t)(mat >> 1) * 128 * 128;
    int lane = idx & 63;
    int tn = (idx >> 6) & 7;
    int kk = idx >> 9;
    int n = tn * 16 + (lane & 15);
    int kb = kk * 32 + (lane >> 4) * 8;
    unsigned int p[4];
#pragma unroll
    for (int jj = 0; jj < 4; ++jj) {
        unsigned short lo = f2bf(W[(kb + 2 * jj) * 128 + n]);
        unsigned short hi = f2bf(W[(kb + 2 * jj + 1) * 128 + n]);
        p[jj] = (unsigned int)lo | ((unsigned int)hi << 16);
    }
    Wf[t] = make_uint4(p[0], p[1], p[2], p[3]);
}

// ---------------- aggregation (bf16, 8 edge slots, 2 uint4/lane) ----------------
// One wave per node. grp=lane>>3 is the edge slot (8 edges in flight); sub=lane&7:
// lane loads row chunks sub and sub+8 (two independent 16B loads, 2KB/wave-iter).
__global__ __launch_bounds__(256) void agg_bf16w8(const unsigned int* __restrict__ h,
                                                  const int* __restrict__ row_ptr,
                                                  const int* __restrict__ col,
                                                  unsigned int* __restrict__ u) {
    int node = blockIdx.x * 4 + (threadIdx.x >> 6);
    int lane = threadIdx.x & 63;
    if (node >= NN) return;
    const int grp = lane >> 3;
    const int sub = lane & 7;
    const uint4* hv = (const uint4*)h;

    float a[16] = {};
    if (grp == 0) {
        uint4 v0 = hv[(size_t)node * 16 + sub];
        uint4 v1 = hv[(size_t)node * 16 + 8 + sub];
        a[0] += bf_lo(v0.x); a[1] += bf_hi(v0.x);
        a[2] += bf_lo(v0.y); a[3] += bf_hi(v0.y);
        a[4] += bf_lo(v0.z); a[5] += bf_hi(v0.z);
        a[6] += bf_lo(v0.w); a[7] += bf_hi(v0.w);
        a[8] += bf_lo(v1.x); a[9] += bf_hi(v1.x);
        a[10] += bf_lo(v1.y); a[11] += bf_hi(v1.y);
        a[12] += bf_lo(v1.z); a[13] += bf_hi(v1.z);
        a[14] += bf_lo(v1.w); a[15] += bf_hi(v1.w);
    }
    int s = row_ptr[node], e = row_ptr[node + 1];
    for (int j = s + grp; j < e; j += 8) {
        int c = col[j];
        uint4 v0 = hv[(size_t)c * 16 + sub];
        uint4 v1 = hv[(size_t)c * 16 + 8 + sub];
        a[0] += bf_lo(v0.x); a[1] += bf_hi(v0.x);
        a[2] += bf_lo(v0.y); a[3] += bf_hi(v0.y);
        a[4] += bf_lo(v0.z); a[5] += bf_hi(v0.z);
        a[6] += bf_lo(v0.w); a[7] += bf_hi(v0.w);
        a[8] += bf_lo(v1.x); a[9] += bf_hi(v1.x);
        a[10] += bf_lo(v1.y); a[11] += bf_hi(v1.y);
        a[12] += bf_lo(v1.z); a[13] += bf_hi(v1.z);
        a[14] += bf_lo(v1.w); a[15] += bf_hi(v1.w);
    }
#pragma unroll
    for (int t = 0; t < 16; ++t) {
        a[t] += __shfl_xor(a[t], 8);
        a[t] += __shfl_xor(a[t], 16);
        a[t] += __shfl_xor(a[t], 32);
    }
    if (grp == 0) {
        uint4 o0, o1;
        o0.x = (unsigned int)f2bf(a[0]) | ((unsigned int)f2bf(a[1]) << 16);
        o0.y = (unsigned int)f2bf(a[2]) | ((unsigned int)f2bf(a[3]) << 16);
        o0.z = (unsigned int)f2bf(a[4]) | ((unsigned int)f2bf(a[5]) << 16);
        o0.w = (unsigned int)f2bf(a[6]) | ((unsigned int)f2bf(a[7]) << 16);
        o1.x = (unsigned int)f2bf(a[8]) | ((unsigned int)f2bf(a[9]) << 16);
        o1.y = (unsigned int)f2bf(a[10]) | ((unsigned int)f2bf(a[11]) << 16);
        o1.z = (unsigned int)f2bf(a[12]) | ((unsigned int)f2bf(a[13]) << 16);
        o1.w = (unsigned int)f2bf(a[14]) | ((unsigned int)f2bf(a[15]) << 16);
        ((uint4*)u)[(size_t)node * 16 + sub] = o0;
        ((uint4*)u)[(size_t)node * 16 + 8 + sub] = o1;
    }
}

// ---------------- fused MLP: Out = leaky(BN(leaky(A@W1+b1))@W2 + b2) ----------------
__global__ __launch_bounds__(256) void mlp_fused(const unsigned short* __restrict__ A,
                                                 const uint4* __restrict__ W1f,
                                                 const uint4* __restrict__ W2f,
                                                 const float* __restrict__ b1,
                                                 const float* __restrict__ g,
                                                 const float* __restrict__ beta,
                                                 const float* __restrict__ rm,
                                                 const float* __restrict__ rv,
                                                 const float* __restrict__ b2,
                                                 unsigned short* __restrict__ Out) {
    __shared__ unsigned short aL[128 * ASTR];
    __shared__ unsigned short mL[4][32 * ASTR];
    const int tid = threadIdx.x;
    const int rb = blockIdx.x * 128;

    const uint4* Ag = (const uint4*)(A + (size_t)rb * 128);
#pragma unroll
    for (int it = 0; it < 8; ++it) {
        int idx = it * 256 + tid;
        int r = idx >> 4, c = idx & 15;
        uint4 v = make_uint4(0u, 0u, 0u, 0u);
        if (rb + r < NN) v = Ag[idx];
        *(uint4*)&aL[r * ASTR + c * 8] = v;
    }
    __syncthreads();

    const int wid = tid >> 6, lane = tid & 63;
    const int ml = lane & 15, q = lane >> 4;
    const int m0 = wid * 32;

    floatx4 acc[2][8] = {};
#pragma unroll
    for (int kk = 0; kk < 4; ++kk) {
        short8 af[2];
#pragma unroll
        for (int t = 0; t < 2; ++t)
            af[t] = *(const short8*)&aL[(m0 + t * 16 + ml) * ASTR + kk * 32 + q * 8];
#pragma unroll
        for (int tn = 0; tn < 8; ++tn) {
            uint4 bq = W1f[(kk * 8 + tn) * 64 + lane];
            short8 bf = *(short8*)&bq;
            acc[0][tn] = __builtin_amdgcn_mfma_f32_16x16x32_bf16(af[0], bf, acc[0][tn], 0, 0, 0);
            acc[1][tn] = __builtin_amdgcn_mfma_f32_16x16x32_bf16(af[1], bf, acc[1][tn], 0, 0, 0);
        }
    }

#pragma unroll
    for (int tn = 0; tn < 8; ++tn) {
        int c = tn * 16 + ml;
        float s = g[c] * rsqrtf(rv[c] + BN_EPS);
        float sh = beta[c] - s * rm[c];
        float bv = b1[c];
#pragma unroll
        for (int t = 0; t < 2; ++t)
#pragma unroll
            for (int r = 0; r < 4; ++r) {
                float val = leaky(acc[t][tn][r] + bv);
                val = s * val + sh;
                mL[wid][(t * 16 + q * 4 + r) * ASTR + c] = f2bf(val);
            }
    }
    __syncthreads();

    floatx4 acc2[2][8] = {};
#pragma unroll
    for (int kk = 0; kk < 4; ++kk) {
        short8 af[2];
#pragma unroll
        for (int t = 0; t < 2; ++t)
            af[t] = *(const short8*)&mL[wid][(t * 16 + ml) * ASTR + kk * 32 + q * 8];
#pragma unroll
        for (int tn = 0; tn < 8; ++tn) {
            uint4 bq = W2f[(kk * 8 + tn) * 64 + lane];
            short8 bf = *(short8*)&bq;
            acc2[0][tn] = __builtin_amdgcn_mfma_f32_16x16x32_bf16(af[0], bf, acc2[0][tn], 0, 0, 0);
            acc2[1][tn] = __builtin_amdgcn_mfma_f32_16x16x32_bf16(af[1], bf, acc2[1][tn], 0, 0, 0);
        }
    }

#pragma unroll
    for (int tn = 0; tn < 8; ++tn) {
        int c = tn * 16 + ml;
        float bv = b2[c];
#pragma unroll
        for (int t = 0; t < 2; ++t)
#pragma unroll
            for (int r = 0; r < 4; ++r) {
                int row = rb + m0 + t * 16 + q * 4 + r;
                if (row < NN)
                    Out[(size_t)row * 128 + c] = f2bf(leaky(acc2[t][tn][r] + bv));
            }
    }
}

// ---------------- pooling + BN ----------------
__global__ __launch_bounds__(256) void pool_bf16(const unsigned int* __restrict__ h,
                                                 const int* __restrict__ gstart,
                                                 const float* __restrict__ bng,
                                                 const float* __restrict__ bnb,
                                                 const float* __restrict__ bnrm,
                                                 const float* __restrict__ bnrv,
                                                 float* __restrict__ pooled) {
    __shared__ float lds[4][128];
    int g = blockIdx.x;
    int wid = threadIdx.x >> 6, lane = threadIdx.x & 63;
    int s = gstart[g], e = gstart[g + 1];
    float ax = 0.f, ay = 0.f;
    for (int n = s + wid; n < e; n += 4) {
        unsigned int v = h[(size_t)n * 64 + lane];
        ax += bf_lo(v);
        ay += bf_hi(v);
    }
    lds[wid][lane * 2] = ax;
    lds[wid][lane * 2 + 1] = ay;
    __syncthreads();
    if (wid == 0) {
#pragma unroll
        for (int t = 0; t < 2; ++t) {
            int c = lane * 2 + t;
            float acc = lds[0][c] + lds[1][c] + lds[2][c] + lds[3][c];
            pooled[g * 128 + c] = bng[c] * (acc - bnrm[c]) * rsqrtf(bnrv[c] + BN_EPS) + bnb[c];
        }
    }
}

__global__ __launch_bounds__(64) void final_kernel(const float* __restrict__ pooled,
                                                   const float* __restrict__ fcW,
                                                   const float* __restrict__ fcb,
                                                   float* __restrict__ out) {
    int g = blockIdx.x;
    int l = threadIdx.x;
    float acc = fcb[l];
#pragma unroll 8
    for (int c = 0; c < HH; ++c) acc += pooled[g * 128 + c] * fcW[c * LATENT + l];
    out[g * LATENT + l] = acc;
}

extern "C" void kernel_launch(void* const* d_in, const int* in_sizes, int n_in,
                              void* d_out, int out_size, void* d_ws, size_t ws_size,
                              hipStream_t stream) {
    const float* x = (const float*)d_in[0];
    const int* ei = (const int*)d_in[1];
    const int* batch = (const int*)d_in[2];
    const float* W1 = (const float*)d_in[3];
    const float* b1 = (const float*)d_in[4];
    const float* g1 = (const float*)d_in[5];
    const float* beta1 = (const float*)d_in[6];
    const float* rm1 = (const float*)d_in[7];
    const float* rv1 = (const float*)d_in[8];
    const float* W2 = (const float*)d_in[9];
    const float* b2 = (const float*)d_in[10];
    const float* bn_g = (const float*)d_in[11];
    const float* bn_b = (const float*)d_in[12];
    const float* bn_rm = (const float*)d_in[13];
    const float* bn_rv = (const float*)d_in[14];
    const float* fcW = (const float*)d_in[15];
    const float* fcb = (const float*)d_in[16];
    float* out = (float*)d_out;

    const int* src = ei;
    const int* dst = ei + EE;

    char* w = (char*)d_ws;
    size_t off = 0;
    auto alloc = [&](size_t bytes) -> char* {
        char* p = w + off;
        off += (bytes + 1023) & ~(size_t)1023;
        return p;
    };
    unsigned int* hx = (unsigned int*)alloc(4 * (size_t)NN * 64);
    unsigned int* ubuf = (unsigned int*)alloc(4 * (size_t)NN * 64);
    unsigned int* hbuf = (unsigned int*)alloc(4 * (size_t)NN * 64);
    uint4* Wf = (uint4*)alloc(16 * (size_t)6 * 2048);
    int* deg = (int*)alloc(4 * (size_t)NN);
    int* row_ptr = (int*)alloc(4 * (size_t)(NN + 1));
    int* rank = (int*)alloc(4 * (size_t)EE);
    int* col = (int*)alloc(4 * (size_t)EE);
    int* bsum = (int*)alloc(4 * 512);
    int* gstart = (int*)alloc(4 * (GG + 1));
    float* pooled = (float*)alloc(sizeof(float) * GG * 128);
    (void)ws_size; (void)in_sizes; (void)n_in; (void)out_size;

    hipMemsetAsync(deg, 0, 4 * (size_t)NN, stream);
    hist_kernel<<<(EE + 255) / 256, 256, 0, stream>>>(dst, deg, rank);
    scan1<<<NB_SCAN, 256, 0, stream>>>(deg, bsum);
    scan2<<<1, 512, 0, stream>>>(bsum, row_ptr);
    scan3<<<NB_SCAN, 256, 0, stream>>>(deg, bsum, row_ptr);
    fill2<<<(EE + 255) / 256, 256, 0, stream>>>(src, dst, rank, row_ptr, col);
    gstart_kernel<<<(NN + 255) / 256, 256, 0, stream>>>(batch, gstart);

    cvtX<<<(NN * 64 + 255) / 256, 256, 0, stream>>>((const float2*)x, hx);
    cvtWall<<<48, 256, 0, stream>>>(W1, W2, Wf);

    const int gblocks = (NN + 127) / 128;
    const unsigned int* hcur = hx;
    for (int i = 0; i < LL; ++i) {
        agg_bf16w8<<<(NN + 3) / 4, 256, 0, stream>>>(hcur, row_ptr, col, ubuf);
        mlp_fused<<<gblocks, 256, 0, stream>>>((const unsigned short*)ubuf,
                                               Wf + (size_t)(2 * i) * 2048,
                                               Wf + (size_t)(2 * i + 1) * 2048,
                                               b1 + i * HH, g1 + i * HH, beta1 + i * HH,
                                               rm1 + i * HH, rv1 + i * HH, b2 + i * HH,
                                               (unsigned short*)hbuf);
        hcur = hbuf;
    }
    pool_bf16<<<GG, 256, 0, stream>>>(hbuf, gstart, bn_g, bn_b, bn_rm, bn_rv, pooled);
    final_kernel<<<GG, 64, 0, stream>>>(pooled, fcW, fcb, out);
}